// Round 3
// baseline (228.167 us; speedup 1.0000x reference)
//
#include <hip/hip_runtime.h>
#include <stdint.h>

#define H_ 96
#define W_ 96
#define C_ 256
#define O_ 256
#define N_ 2
#define HW_ (H_*W_)          // 9216
#define M_ (N_*HW_)          // 18432
#define GK 2304              // C_*9

typedef __bf16 bf16x8 __attribute__((ext_vector_type(8)));
typedef float f32x4 __attribute__((ext_vector_type(4)));
typedef float f32x2 __attribute__((ext_vector_type(2)));
typedef unsigned short us4 __attribute__((ext_vector_type(4)));
typedef unsigned short us8 __attribute__((ext_vector_type(8)));

__device__ __forceinline__ unsigned short f2bf(float f) {
  union { float f; unsigned int u; } v; v.f = f;
  unsigned int u = v.u;
  return (unsigned short)((u + 0x7fffu + ((u >> 16) & 1u)) >> 16);
}
__device__ __forceinline__ float bf2f(unsigned short h) {
  union { unsigned int u; float f; } v; v.u = ((unsigned int)h) << 16;
  return v.f;
}
// two packed bf16 (one u32) -> two f32
__device__ __forceinline__ f32x2 bfpair(unsigned int a) {
  union { unsigned int u; float f; } lo, hi;
  lo.u = a << 16;
  hi.u = a & 0xffff0000u;
  f32x2 r; r[0] = lo.f; r[1] = hi.f;
  return r;
}

// ---------------- Kernel 1: combined prep.
// v4: transpose retiled 64p x 128c (576 blocks, was 288 of 128p x 128c) ->
// grid 1008 total (~4 blocks/CU, was ~2.8 with half the machine idle on the
// 288-block transpose section). Both global sides keep >=256B granules.
__global__ __launch_bounds__(256) void k_pre(const float* __restrict__ x,
                                             const float* __restrict__ w_df,
                                             const float* __restrict__ w_tm,
                                             const float* __restrict__ w_tr,
                                             unsigned short* __restrict__ xt,
                                             unsigned short* __restrict__ wfrag,
                                             unsigned short* __restrict__ w6p) {
  const int b = blockIdx.x;
  const int tid = threadIdx.x;
  if (b < 576) {
    __shared__ unsigned short tile[64][130];
    const int pt = b % 144;          // 144 p-tiles of 64
    const int ch = (b / 144) & 1;    // 2 c-halves of 128
    const int n  = b / 288;
    const int p0 = pt * 64, c0 = ch * 128;
    const float* xp = x + (size_t)n * C_ * HW_;
    unsigned short* xtp = xt + (size_t)n * C_ * HW_;
    const int tx = tid & 15, ty = tid >> 4;  // 16 p-chunks x 16 c-rows
#pragma unroll
    for (int pass = 0; pass < 8; pass++) {
      const int c = pass * 16 + ty;
      const f32x4 v = *(const f32x4*)(xp + (size_t)(c0 + c) * HW_ + p0 + tx * 4);
#pragma unroll
      for (int i = 0; i < 4; i++) tile[tx * 4 + i][c] = f2bf(v[i]);
    }
    __syncthreads();
    const int l32 = tid & 31, pr = tid >> 5;  // 32 c-chunks x 8 p-rows
#pragma unroll
    for (int pass = 0; pass < 8; pass++) {
      const int p = pass * 8 + pr;
      us4 v;
#pragma unroll
      for (int i = 0; i < 4; i++) v[i] = tile[p][l32 * 4 + i];
      *(us4*)(xtp + (size_t)(p0 + p) * C_ + c0 + l32 * 4) = v;
    }
  } else if (b < 864) {
    const int base = (b - 576) * 2048 + tid * 8;  // < 589824
    const int l  = (base >> 3) & 63;
    const int g  = (base >> 9) & 15;
    const int ks = (base >> 13) & 7;
    const int t  = base >> 16;
    const int o  = g * 16 + (l & 15);
    const int c  = ks * 32 + (l >> 4) * 8;
    us8 res;
#pragma unroll
    for (int j = 0; j < 8; j++) res[j] = f2bf(w_df[(size_t)(o * 256 + c + j) * 9 + t]);
    *(us8*)(wfrag + base) = res;
  } else {
    int idx = (b - 864) * 256 + tid;   // < 9*16*256 = 36864
    int t = idx >> 12;
    int r = idx & 4095;
    int j = r >> 8;
    int c = r & 255;
    float v = 0.f;
    if (j < 4) v = w_tm[(size_t)(j * C_ + c) * 9 + t];
    else if (j < 6) v = w_tr[(size_t)((j - 4) * C_ + c) * 9 + t];
    w6p[idx] = f2bf(v);
  }
}

// ---------------- Kernel 2: FUSED offsets + sample + GEMM + BN + res + ReLU.
// v4: 512 threads / 8 waves, 32m x 128o tile (O split in two), grid 1152 =
// 4.5 blocks/CU; LDS 39KB -> 4 blocks co-resident = 32 waves/CU (was 9).
// Wave-tile 32m x 16o: 1 bv frag/ks (bv regs halve; launch_bounds(512,8)
// pins VGPR<=64 for full 8 waves/SIMD). Wfrag total stream unchanged
// (each block reads only its O-half). Lerp/corner work duplicates across
// the two O-half blocks -- paid from idle VALU/L2 headroom; O-half pairs
// of the same m-strip land on the same XCD (slot decode) so duplicated
// corner reads are L2 hits. Still ONE barrier per tap.
__global__ __launch_bounds__(512, 8) void k_fused(const unsigned short* __restrict__ xt,
                                                  const unsigned short* __restrict__ Wfrag,
                                                  const unsigned short* __restrict__ w6p,
                                                  const float* __restrict__ b_tm,
                                                  const float* __restrict__ b_tr,
                                                  const float* __restrict__ xres,
                                                  const float* __restrict__ gamma,
                                                  const float* __restrict__ beta,
                                                  const float* __restrict__ mean,
                                                  const float* __restrict__ var,
                                                  float* __restrict__ out) {
  __shared__ unsigned short As[2][32 * 256] __attribute__((aligned(16)));  // 32KB
  __shared__ float sred[8][16][8];
  __shared__ float coords_s[32][9][2];
  const int tid = threadIdx.x;
  const int wave = tid >> 6, lane = tid & 63;
  const int row = lane & 15, quad = lane >> 4;
  // slot = m-tile*2 + o-half; consecutive slots on one XCD -> both O-halves
  // of an m-strip (and neighboring strips) share corner data in that XCD's L2.
  const int slot = (blockIdx.x & 7) * 144 + (blockIdx.x >> 3);
  const int bm = slot >> 1;
  const int bo = slot & 1;        // which 128-o half
  const int m0 = bm * 32;
  const int n = m0 / HW_;   // 32 | 9216: tile never crosses n
  const int sr = tid >> 4;  // staging row 0..31 (one row per thread)
  const int cg = tid & 15;  // staging 16-channel group

  // ---- Prologue: offset conv for the 32-m strip ----
  // waves 0-3 -> rows 0..15, waves 4-7 -> rows 16..31; each wave a 64-ch quarter.
  {
    const int hw0 = m0 - n * HW_;
    const int h = hw0 / W_;
    const int w0 = hw0 - h * W_;  // multiple of 32 (32 | 96)
    const int rh = wave >> 2;     // row half
    const int cq = (wave & 3) * 64;
    f32x4 oacc = {0.f, 0.f, 0.f, 0.f};
    const bf16x8 zero8 = {};
#pragma unroll
    for (int t = 0; t < 9; t++) {
      const int ty = t / 3, tx = t % 3;
      const int y = h + ty - 1;
      if (y < 0 || y >= H_) continue;  // wave-uniform
      const int xx = w0 + rh * 16 + row + tx - 1;
      const bool valid = (xx >= 0) && (xx < W_);
      const int xc = min(max(xx, 0), W_ - 1);
      const unsigned short* arow =
          xt + (size_t)((n * H_ + y) * W_ + xc) * C_ + cq + quad * 8;
      const unsigned short* brow =
          w6p + (size_t)(t * 16 + row) * C_ + cq + quad * 8;
#pragma unroll
      for (int ks = 0; ks < 2; ks++) {
        bf16x8 av = *(const bf16x8*)(const void*)(arow + ks * 32);
        if (!valid) av = zero8;
        bf16x8 bv = *(const bf16x8*)(const void*)(brow + ks * 32);
        oacc = __builtin_amdgcn_mfma_f32_16x16x32_bf16(av, bv, oacc, 0, 0, 0);
      }
    }
    if (row < 6) {
#pragma unroll
      for (int r = 0; r < 4; r++) sred[wave][quad * 4 + r][row] = oacc[r];
    }
  }
  __syncthreads();
  if (wave < 2 && lane < 16) {
    const int rg = wave * 16 + lane;  // global row 0..31
    const int hwm = m0 + rg - n * HW_;
    const int h = hwm / W_, w = hwm - h * W_;
    float a[6];
#pragma unroll
    for (int j = 0; j < 6; j++)
      a[j] = sred[wave * 4 + 0][lane][j] + sred[wave * 4 + 1][lane][j] +
             sred[wave * 4 + 2][lane][j] + sred[wave * 4 + 3][lane][j];
    const float tm0 = a[0] + b_tm[0];
    const float tm1 = a[1] + b_tm[1];
    const float tm2 = a[2] + b_tm[2];
    const float tm3 = a[3] + b_tm[3];
    const float tr0 = a[4] + b_tr[0];
    const float tr1 = a[5] + b_tr[1];
#pragma unroll
    for (int t = 0; t < 9; t++) {
      const float ry = (float)(t / 3) - 1.f;
      const float rx = (float)(t % 3) - 1.f;
      coords_s[rg][t][0] = (float)h + tr0 + tm0 * ry + tm1 * rx;
      coords_s[rg][t][1] = (float)w + tr1 + tm2 * ry + tm3 * rx;
    }
  }
  __syncthreads();

  // ---- Main loop over 9 taps ----
  f32x4 acc0 = {}, acc1 = {};
  float cw[4];
  int cb[4];
  us8 u0[4], u1[4];  // corner data for row sr, channels cg*16..+7 and +8..+15

#define PREP1(TAP)                                                             \
  {                                                                            \
    const float py = coords_s[sr][TAP][0];                                     \
    const float px = coords_s[sr][TAP][1];                                     \
    const float fy = floorf(py), fx = floorf(px);                              \
    const float wy = py - fy, wx = px - fx;                                    \
    const int y0 = (int)fy, x0 = (int)fx;                                      \
    const int y1 = y0 + 1, x1 = x0 + 1;                                        \
    const float vy0 = (y0 >= 0 && y0 < H_) ? 1.f : 0.f;                        \
    const float vy1 = (y1 >= 0 && y1 < H_) ? 1.f : 0.f;                        \
    const float vx0 = (x0 >= 0 && x0 < W_) ? 1.f : 0.f;                        \
    const float vx1 = (x1 >= 0 && x1 < W_) ? 1.f : 0.f;                        \
    cw[0] = (1.f - wy) * (1.f - wx) * vy0 * vx0;                               \
    cw[1] = (1.f - wy) * wx * vy0 * vx1;                                       \
    cw[2] = wy * (1.f - wx) * vy1 * vx0;                                       \
    cw[3] = wy * wx * vy1 * vx1;                                               \
    const int cy0 = min(max(y0, 0), H_ - 1), cy1 = min(max(y1, 0), H_ - 1);    \
    const int cx0 = min(max(x0, 0), W_ - 1), cx1 = min(max(x1, 0), W_ - 1);    \
    cb[0] = ((n * H_ + cy0) * W_ + cx0) * C_;                                  \
    cb[1] = ((n * H_ + cy0) * W_ + cx1) * C_;                                  \
    cb[2] = ((n * H_ + cy1) * W_ + cx0) * C_;                                  \
    cb[3] = ((n * H_ + cy1) * W_ + cx1) * C_;                                  \
  }

#define LOADC1()                                                               \
  {                                                                            \
    const int cc = cg * 16;                                                    \
    u0[0] = *(const us8*)(xt + cb[0] + cc); u1[0] = *(const us8*)(xt + cb[0] + cc + 8); \
    u0[1] = *(const us8*)(xt + cb[1] + cc); u1[1] = *(const us8*)(xt + cb[1] + cc + 8); \
    u0[2] = *(const us8*)(xt + cb[2] + cc); u1[2] = *(const us8*)(xt + cb[2] + cc + 8); \
    u0[3] = *(const us8*)(xt + cb[3] + cc); u1[3] = *(const us8*)(xt + cb[3] + cc + 8); \
  }

  // packed-f32 lerp of one us8 (4 bf16-pairs) -> bf16x8 via RTNE cvt
#define LERP8V(DST, U)                                                         \
  {                                                                            \
    const unsigned int* a0 = (const unsigned int*)&U[0];                       \
    const unsigned int* a1 = (const unsigned int*)&U[1];                       \
    const unsigned int* a2 = (const unsigned int*)&U[2];                       \
    const unsigned int* a3 = (const unsigned int*)&U[3];                       \
    _Pragma("unroll")                                                          \
    for (int p = 0; p < 4; p++) {                                              \
      f32x2 acc = bfpair(a0[p]) * cw[0] + bfpair(a1[p]) * cw[1] +              \
                  bfpair(a2[p]) * cw[2] + bfpair(a3[p]) * cw[3];               \
      DST[p * 2]     = (__bf16)acc[0];                                         \
      DST[p * 2 + 1] = (__bf16)acc[1];                                         \
    }                                                                          \
  }

  PREP1(0);
  LOADC1();

  for (int tap = 0; tap < 9; tap++) {
    unsigned short* __restrict__ asb = As[tap & 1];

    // bv load for ks0 issued FIRST: its L2 latency hides under this wave's
    // lerp, and it is complete by the barrier's vmcnt drain.
    const unsigned short* wfTap =
        Wfrag + (size_t)tap * 65536 + (bo * 8 + wave) * 512 + lane * 8;
    bf16x8 bv = *(const bf16x8*)(const void*)(wfTap);

    // lerp row sr into As[buf] (swizzled slots: slot = (q&24)|((q^sr)&7);
    // (r+16)&7 == r&7 so the read side uses the same slot for row and row+16)
    {
      const int q0 = cg * 2, q1 = cg * 2 + 1;
      const int s0 = (q0 & 24) | ((q0 ^ sr) & 7);
      const int s1 = (q1 & 24) | ((q1 ^ sr) & 7);
      bf16x8 r0, r1;
      LERP8V(r0, u0);
      LERP8V(r1, u1);
      *(bf16x8*)(void*)&asb[sr * 256 + s0 * 8] = r0;
      *(bf16x8*)(void*)&asb[sr * 256 + s1 * 8] = r1;
    }

    __syncthreads();  // ONE barrier per tap

    if (tap < 8) {  // corner prefetch for tap+1, overlapped with the bn stream
      PREP1(tap + 1);
      LOADC1();
    }

#pragma unroll
    for (int ks = 0; ks < 8; ks++) {
      const int q = ks * 4 + quad;
      const int slot = (q & 24) | ((q ^ row) & 7);
      const bf16x8 av0 = *(const bf16x8*)(const void*)&asb[row * 256 + slot * 8];
      const bf16x8 av1 = *(const bf16x8*)(const void*)&asb[(row + 16) * 256 + slot * 8];
      bf16x8 bn;
      if (ks < 7) bn = *(const bf16x8*)(const void*)(wfTap + (size_t)(ks + 1) * 8192);
      acc0 = __builtin_amdgcn_mfma_f32_16x16x32_bf16(av0, bv, acc0, 0, 0, 0);
      acc1 = __builtin_amdgcn_mfma_f32_16x16x32_bf16(av1, bv, acc1, 0, 0, 0);
      if (ks < 7) bv = bn;
    }
    // NO trailing barrier: As double-buffered; next write to As[tap&1] happens
    // after barrier(tap+1), which orders all reads of As[tap&1].
  }

  // ---- Epilogue: BN + residual + ReLU, float4 rows (both m-halves) ----
  const int hwb = m0 - n * HW_ + quad * 4;
  {
    const int o = bo * 128 + wave * 16 + row;
    const float sc = rsqrtf(var[o] + 1e-5f) * gamma[o];
    const float bi = beta[o] - mean[o] * sc;
    const size_t ob0 = (size_t)(n * O_ + o) * HW_ + hwb;
    f32x4 rv = *(const f32x4*)(xres + ob0);
    f32x4 ov;
#pragma unroll
    for (int r = 0; r < 4; r++) ov[r] = fmaxf(acc0[r] * sc + bi + rv[r], 0.f);
    *(f32x4*)(out + ob0) = ov;
    const size_t ob1 = ob0 + 16;  // rows 16..31, same h-strip
    rv = *(const f32x4*)(xres + ob1);
#pragma unroll
    for (int r = 0; r < 4; r++) ov[r] = fmaxf(acc1[r] * sc + bi + rv[r], 0.f);
    *(f32x4*)(out + ob1) = ov;
  }
}

extern "C" void kernel_launch(void* const* d_in, const int* in_sizes, int n_in,
                              void* d_out, int out_size, void* d_ws, size_t ws_size,
                              hipStream_t stream) {
  const float* x     = (const float*)d_in[0];
  const float* w_tm  = (const float*)d_in[2];
  const float* b_tm  = (const float*)d_in[3];
  const float* w_tr  = (const float*)d_in[4];
  const float* b_tr  = (const float*)d_in[5];
  const float* w_df  = (const float*)d_in[6];
  const float* gamma = (const float*)d_in[7];
  const float* beta  = (const float*)d_in[8];
  const float* mean  = (const float*)d_in[9];
  const float* var   = (const float*)d_in[10];
  float* out = (float*)d_out;

  char* ws = (char*)d_ws;
  unsigned short* xt    = (unsigned short*)(ws);                       //  9,437,184 B
  unsigned short* wfrag = (unsigned short*)(ws + 9437184);             //  1,179,648 B
  unsigned short* w6p   = (unsigned short*)(ws + 9437184 + 1179648);   //     73,728 B

  k_pre<<<1008, 256, 0, stream>>>(x, w_df, w_tm, w_tr, xt, wfrag, w6p);
  k_fused<<<1152, 512, 0, stream>>>(xt, wfrag, w6p, b_tm, b_tr, x,
                                    gamma, beta, mean, var, out);
}

// Round 4
// 193.435 us; speedup vs baseline: 1.1796x; 1.1796x over previous
//
#include <hip/hip_runtime.h>
#include <stdint.h>

#define H_ 96
#define W_ 96
#define C_ 256
#define O_ 256
#define N_ 2
#define HW_ (H_*W_)          // 9216
#define M_ (N_*HW_)          // 18432
#define GK 2304              // C_*9

typedef __bf16 bf16x8 __attribute__((ext_vector_type(8)));
typedef float f32x4 __attribute__((ext_vector_type(4)));
typedef float f32x2 __attribute__((ext_vector_type(2)));
typedef unsigned short us4 __attribute__((ext_vector_type(4)));
typedef unsigned short us8 __attribute__((ext_vector_type(8)));

__device__ __forceinline__ unsigned short f2bf(float f) {
  union { float f; unsigned int u; } v; v.f = f;
  unsigned int u = v.u;
  return (unsigned short)((u + 0x7fffu + ((u >> 16) & 1u)) >> 16);
}
__device__ __forceinline__ float bf2f(unsigned short h) {
  union { unsigned int u; float f; } v; v.u = ((unsigned int)h) << 16;
  return v.f;
}
// two packed bf16 (one u32) -> two f32
__device__ __forceinline__ f32x2 bfpair(unsigned int a) {
  union { unsigned int u; float f; } lo, hi;
  lo.u = a << 16;
  hi.u = a & 0xffff0000u;
  f32x2 r; r[0] = lo.f; r[1] = hi.f;
  return r;
}

// ---------------- Kernel 1: combined prep.
// 64p x 128c transpose tiles (576 blocks) -> grid 1008 (~4 blocks/CU).
// Both global sides keep >=256B granules.
__global__ __launch_bounds__(256) void k_pre(const float* __restrict__ x,
                                             const float* __restrict__ w_df,
                                             const float* __restrict__ w_tm,
                                             const float* __restrict__ w_tr,
                                             unsigned short* __restrict__ xt,
                                             unsigned short* __restrict__ wfrag,
                                             unsigned short* __restrict__ w6p) {
  const int b = blockIdx.x;
  const int tid = threadIdx.x;
  if (b < 576) {
    __shared__ unsigned short tile[64][130];
    const int pt = b % 144;          // 144 p-tiles of 64
    const int ch = (b / 144) & 1;    // 2 c-halves of 128
    const int n  = b / 288;
    const int p0 = pt * 64, c0 = ch * 128;
    const float* xp = x + (size_t)n * C_ * HW_;
    unsigned short* xtp = xt + (size_t)n * C_ * HW_;
    const int tx = tid & 15, ty = tid >> 4;  // 16 p-chunks x 16 c-rows
#pragma unroll
    for (int pass = 0; pass < 8; pass++) {
      const int c = pass * 16 + ty;
      const f32x4 v = *(const f32x4*)(xp + (size_t)(c0 + c) * HW_ + p0 + tx * 4);
#pragma unroll
      for (int i = 0; i < 4; i++) tile[tx * 4 + i][c] = f2bf(v[i]);
    }
    __syncthreads();
    const int l32 = tid & 31, pr = tid >> 5;  // 32 c-chunks x 8 p-rows
#pragma unroll
    for (int pass = 0; pass < 8; pass++) {
      const int p = pass * 8 + pr;
      us4 v;
#pragma unroll
      for (int i = 0; i < 4; i++) v[i] = tile[p][l32 * 4 + i];
      *(us4*)(xtp + (size_t)(p0 + p) * C_ + c0 + l32 * 4) = v;
    }
  } else if (b < 864) {
    const int base = (b - 576) * 2048 + tid * 8;  // < 589824
    const int l  = (base >> 3) & 63;
    const int g  = (base >> 9) & 15;
    const int ks = (base >> 13) & 7;
    const int t  = base >> 16;
    const int o  = g * 16 + (l & 15);
    const int c  = ks * 32 + (l >> 4) * 8;
    us8 res;
#pragma unroll
    for (int j = 0; j < 8; j++) res[j] = f2bf(w_df[(size_t)(o * 256 + c + j) * 9 + t]);
    *(us8*)(wfrag + base) = res;
  } else {
    int idx = (b - 864) * 256 + tid;   // < 9*16*256 = 36864
    int t = idx >> 12;
    int r = idx & 4095;
    int j = r >> 8;
    int c = r & 255;
    float v = 0.f;
    if (j < 4) v = w_tm[(size_t)(j * C_ + c) * 9 + t];
    else if (j < 6) v = w_tr[(size_t)((j - 4) * C_ + c) * 9 + t];
    w6p[idx] = f2bf(v);
  }
}

// ---------------- Kernel 2: FUSED offsets + sample + GEMM + BN + res + ReLU.
// v5 = v4 with launch_bounds(512, 4).
// Session-empirical law: VGPR cap = 256 / (min waves per EU).
//   (512,8) -> cap 32 -> MASSIVE spill (round 3: hbm_bytes 49->199MB, 140us).
//   (512,4) -> cap 64 -> fits spill-free (proved by v3 at exactly 64 VGPR).
// 2 blocks/CU resident (16 waves/CU), grid 1152 = 4.5 blocks/CU keeps all
// CUs fed. 32m x 128o tile, wave-tile 32m x 16o, ONE barrier per tap.
__global__ __launch_bounds__(512, 4) void k_fused(const unsigned short* __restrict__ xt,
                                                  const unsigned short* __restrict__ Wfrag,
                                                  const unsigned short* __restrict__ w6p,
                                                  const float* __restrict__ b_tm,
                                                  const float* __restrict__ b_tr,
                                                  const float* __restrict__ xres,
                                                  const float* __restrict__ gamma,
                                                  const float* __restrict__ beta,
                                                  const float* __restrict__ mean,
                                                  const float* __restrict__ var,
                                                  float* __restrict__ out) {
  __shared__ unsigned short As[2][32 * 256] __attribute__((aligned(16)));  // 32KB
  __shared__ float sred[8][16][8];
  __shared__ float coords_s[32][9][2];
  const int tid = threadIdx.x;
  const int wave = tid >> 6, lane = tid & 63;
  const int row = lane & 15, quad = lane >> 4;
  // slot = m-tile*2 + o-half; consecutive slots on one XCD -> both O-halves
  // of an m-strip (and neighboring strips) share corner data in that XCD's L2.
  const int slot = (blockIdx.x & 7) * 144 + (blockIdx.x >> 3);
  const int bm = slot >> 1;
  const int bo = slot & 1;        // which 128-o half
  const int m0 = bm * 32;
  const int n = m0 / HW_;   // 32 | 9216: tile never crosses n
  const int sr = tid >> 4;  // staging row 0..31 (one row per thread)
  const int cg = tid & 15;  // staging 16-channel group

  // ---- Prologue: offset conv for the 32-m strip ----
  // waves 0-3 -> rows 0..15, waves 4-7 -> rows 16..31; each wave a 64-ch quarter.
  {
    const int hw0 = m0 - n * HW_;
    const int h = hw0 / W_;
    const int w0 = hw0 - h * W_;  // multiple of 32 (32 | 96)
    const int rh = wave >> 2;     // row half
    const int cq = (wave & 3) * 64;
    f32x4 oacc = {0.f, 0.f, 0.f, 0.f};
    const bf16x8 zero8 = {};
#pragma unroll
    for (int t = 0; t < 9; t++) {
      const int ty = t / 3, tx = t % 3;
      const int y = h + ty - 1;
      if (y < 0 || y >= H_) continue;  // wave-uniform
      const int xx = w0 + rh * 16 + row + tx - 1;
      const bool valid = (xx >= 0) && (xx < W_);
      const int xc = min(max(xx, 0), W_ - 1);
      const unsigned short* arow =
          xt + (size_t)((n * H_ + y) * W_ + xc) * C_ + cq + quad * 8;
      const unsigned short* brow =
          w6p + (size_t)(t * 16 + row) * C_ + cq + quad * 8;
#pragma unroll
      for (int ks = 0; ks < 2; ks++) {
        bf16x8 av = *(const bf16x8*)(const void*)(arow + ks * 32);
        if (!valid) av = zero8;
        bf16x8 bv = *(const bf16x8*)(const void*)(brow + ks * 32);
        oacc = __builtin_amdgcn_mfma_f32_16x16x32_bf16(av, bv, oacc, 0, 0, 0);
      }
    }
    if (row < 6) {
#pragma unroll
      for (int r = 0; r < 4; r++) sred[wave][quad * 4 + r][row] = oacc[r];
    }
  }
  __syncthreads();
  if (wave < 2 && lane < 16) {
    const int rg = wave * 16 + lane;  // global row 0..31
    const int hwm = m0 + rg - n * HW_;
    const int h = hwm / W_, w = hwm - h * W_;
    float a[6];
#pragma unroll
    for (int j = 0; j < 6; j++)
      a[j] = sred[wave * 4 + 0][lane][j] + sred[wave * 4 + 1][lane][j] +
             sred[wave * 4 + 2][lane][j] + sred[wave * 4 + 3][lane][j];
    const float tm0 = a[0] + b_tm[0];
    const float tm1 = a[1] + b_tm[1];
    const float tm2 = a[2] + b_tm[2];
    const float tm3 = a[3] + b_tm[3];
    const float tr0 = a[4] + b_tr[0];
    const float tr1 = a[5] + b_tr[1];
#pragma unroll
    for (int t = 0; t < 9; t++) {
      const float ry = (float)(t / 3) - 1.f;
      const float rx = (float)(t % 3) - 1.f;
      coords_s[rg][t][0] = (float)h + tr0 + tm0 * ry + tm1 * rx;
      coords_s[rg][t][1] = (float)w + tr1 + tm2 * ry + tm3 * rx;
    }
  }
  __syncthreads();

  // ---- Main loop over 9 taps ----
  f32x4 acc0 = {}, acc1 = {};
  float cw[4];
  int cb[4];
  us8 u0[4], u1[4];  // corner data for row sr, channels cg*16..+7 and +8..+15

#define PREP1(TAP)                                                             \
  {                                                                            \
    const float py = coords_s[sr][TAP][0];                                     \
    const float px = coords_s[sr][TAP][1];                                     \
    const float fy = floorf(py), fx = floorf(px);                              \
    const float wy = py - fy, wx = px - fx;                                    \
    const int y0 = (int)fy, x0 = (int)fx;                                      \
    const int y1 = y0 + 1, x1 = x0 + 1;                                        \
    const float vy0 = (y0 >= 0 && y0 < H_) ? 1.f : 0.f;                        \
    const float vy1 = (y1 >= 0 && y1 < H_) ? 1.f : 0.f;                        \
    const float vx0 = (x0 >= 0 && x0 < W_) ? 1.f : 0.f;                        \
    const float vx1 = (x1 >= 0 && x1 < W_) ? 1.f : 0.f;                        \
    cw[0] = (1.f - wy) * (1.f - wx) * vy0 * vx0;                               \
    cw[1] = (1.f - wy) * wx * vy0 * vx1;                                       \
    cw[2] = wy * (1.f - wx) * vy1 * vx0;                                       \
    cw[3] = wy * wx * vy1 * vx1;                                               \
    const int cy0 = min(max(y0, 0), H_ - 1), cy1 = min(max(y1, 0), H_ - 1);    \
    const int cx0 = min(max(x0, 0), W_ - 1), cx1 = min(max(x1, 0), W_ - 1);    \
    cb[0] = ((n * H_ + cy0) * W_ + cx0) * C_;                                  \
    cb[1] = ((n * H_ + cy0) * W_ + cx1) * C_;                                  \
    cb[2] = ((n * H_ + cy1) * W_ + cx0) * C_;                                  \
    cb[3] = ((n * H_ + cy1) * W_ + cx1) * C_;                                  \
  }

#define LOADC1()                                                               \
  {                                                                            \
    const int cc = cg * 16;                                                    \
    u0[0] = *(const us8*)(xt + cb[0] + cc); u1[0] = *(const us8*)(xt + cb[0] + cc + 8); \
    u0[1] = *(const us8*)(xt + cb[1] + cc); u1[1] = *(const us8*)(xt + cb[1] + cc + 8); \
    u0[2] = *(const us8*)(xt + cb[2] + cc); u1[2] = *(const us8*)(xt + cb[2] + cc + 8); \
    u0[3] = *(const us8*)(xt + cb[3] + cc); u1[3] = *(const us8*)(xt + cb[3] + cc + 8); \
  }

  // packed-f32 lerp of one us8 (4 bf16-pairs) -> bf16x8 via RTNE cvt
#define LERP8V(DST, U)                                                         \
  {                                                                            \
    const unsigned int* a0 = (const unsigned int*)&U[0];                       \
    const unsigned int* a1 = (const unsigned int*)&U[1];                       \
    const unsigned int* a2 = (const unsigned int*)&U[2];                       \
    const unsigned int* a3 = (const unsigned int*)&U[3];                       \
    _Pragma("unroll")                                                          \
    for (int p = 0; p < 4; p++) {                                              \
      f32x2 acc = bfpair(a0[p]) * cw[0] + bfpair(a1[p]) * cw[1] +              \
                  bfpair(a2[p]) * cw[2] + bfpair(a3[p]) * cw[3];               \
      DST[p * 2]     = (__bf16)acc[0];                                         \
      DST[p * 2 + 1] = (__bf16)acc[1];                                         \
    }                                                                          \
  }

  PREP1(0);
  LOADC1();

  for (int tap = 0; tap < 9; tap++) {
    unsigned short* __restrict__ asb = As[tap & 1];

    // bv load for ks0 issued FIRST: its L2 latency hides under this wave's
    // lerp, and it is complete by the barrier's vmcnt drain.
    const unsigned short* wfTap =
        Wfrag + (size_t)tap * 65536 + (bo * 8 + wave) * 512 + lane * 8;
    bf16x8 bv = *(const bf16x8*)(const void*)(wfTap);

    // lerp row sr into As[buf] (swizzled slots: slot = (q&24)|((q^sr)&7);
    // (r+16)&7 == r&7 so the read side uses the same slot for row and row+16)
    {
      const int q0 = cg * 2, q1 = cg * 2 + 1;
      const int s0 = (q0 & 24) | ((q0 ^ sr) & 7);
      const int s1 = (q1 & 24) | ((q1 ^ sr) & 7);
      bf16x8 r0, r1;
      LERP8V(r0, u0);
      LERP8V(r1, u1);
      *(bf16x8*)(void*)&asb[sr * 256 + s0 * 8] = r0;
      *(bf16x8*)(void*)&asb[sr * 256 + s1 * 8] = r1;
    }

    __syncthreads();  // ONE barrier per tap

    if (tap < 8) {  // corner prefetch for tap+1, overlapped with the bn stream
      PREP1(tap + 1);
      LOADC1();
    }

#pragma unroll
    for (int ks = 0; ks < 8; ks++) {
      const int q = ks * 4 + quad;
      const int slot = (q & 24) | ((q ^ row) & 7);
      const bf16x8 av0 = *(const bf16x8*)(const void*)&asb[row * 256 + slot * 8];
      const bf16x8 av1 = *(const bf16x8*)(const void*)&asb[(row + 16) * 256 + slot * 8];
      bf16x8 bn;
      if (ks < 7) bn = *(const bf16x8*)(const void*)(wfTap + (size_t)(ks + 1) * 8192);
      acc0 = __builtin_amdgcn_mfma_f32_16x16x32_bf16(av0, bv, acc0, 0, 0, 0);
      acc1 = __builtin_amdgcn_mfma_f32_16x16x32_bf16(av1, bv, acc1, 0, 0, 0);
      if (ks < 7) bv = bn;
    }
    // NO trailing barrier: As double-buffered; next write to As[tap&1] happens
    // after barrier(tap+1), which orders all reads of As[tap&1].
  }

  // ---- Epilogue: BN + residual + ReLU, float4 rows (both m-halves) ----
  const int hwb = m0 - n * HW_ + quad * 4;
  {
    const int o = bo * 128 + wave * 16 + row;
    const float sc = rsqrtf(var[o] + 1e-5f) * gamma[o];
    const float bi = beta[o] - mean[o] * sc;
    const size_t ob0 = (size_t)(n * O_ + o) * HW_ + hwb;
    f32x4 rv = *(const f32x4*)(xres + ob0);
    f32x4 ov;
#pragma unroll
    for (int r = 0; r < 4; r++) ov[r] = fmaxf(acc0[r] * sc + bi + rv[r], 0.f);
    *(f32x4*)(out + ob0) = ov;
    const size_t ob1 = ob0 + 16;  // rows 16..31, same h-strip
    rv = *(const f32x4*)(xres + ob1);
#pragma unroll
    for (int r = 0; r < 4; r++) ov[r] = fmaxf(acc1[r] * sc + bi + rv[r], 0.f);
    *(f32x4*)(out + ob1) = ov;
  }
}

extern "C" void kernel_launch(void* const* d_in, const int* in_sizes, int n_in,
                              void* d_out, int out_size, void* d_ws, size_t ws_size,
                              hipStream_t stream) {
  const float* x     = (const float*)d_in[0];
  const float* w_tm  = (const float*)d_in[2];
  const float* b_tm  = (const float*)d_in[3];
  const float* w_tr  = (const float*)d_in[4];
  const float* b_tr  = (const float*)d_in[5];
  const float* w_df  = (const float*)d_in[6];
  const float* gamma = (const float*)d_in[7];
  const float* beta  = (const float*)d_in[8];
  const float* mean  = (const float*)d_in[9];
  const float* var   = (const float*)d_in[10];
  float* out = (float*)d_out;

  char* ws = (char*)d_ws;
  unsigned short* xt    = (unsigned short*)(ws);                       //  9,437,184 B
  unsigned short* wfrag = (unsigned short*)(ws + 9437184);             //  1,179,648 B
  unsigned short* w6p   = (unsigned short*)(ws + 9437184 + 1179648);   //     73,728 B

  k_pre<<<1008, 256, 0, stream>>>(x, w_df, w_tm, w_tr, xt, wfrag, w6p);
  k_fused<<<1152, 512, 0, stream>>>(xt, wfrag, w6p, b_tm, b_tr, x,
                                    gamma, beta, mean, var, out);
}

// Round 5
// 184.227 us; speedup vs baseline: 1.2385x; 1.0500x over previous
//
#include <hip/hip_runtime.h>
#include <stdint.h>

#define H_ 96
#define W_ 96
#define C_ 256
#define O_ 256
#define N_ 2
#define HW_ (H_*W_)          // 9216
#define M_ (N_*HW_)          // 18432
#define GK 2304              // C_*9

typedef _Float16 f16x8 __attribute__((ext_vector_type(8)));
typedef _Float16 f16x2 __attribute__((ext_vector_type(2)));
typedef float f32x4 __attribute__((ext_vector_type(4)));
typedef unsigned short us4 __attribute__((ext_vector_type(4)));
typedef unsigned short us8 __attribute__((ext_vector_type(8)));

__device__ __forceinline__ unsigned short f2h(float f) {
  union { _Float16 h; unsigned short u; } v;
  v.h = (_Float16)f;
  return v.u;
}

// ---------------- Kernel 1: combined prep (fp16 everywhere now).
// 64p x 128c transpose tiles (576 blocks) -> grid 1008 (~4 blocks/CU).
// Both global sides keep >=256B granules.
__global__ __launch_bounds__(256) void k_pre(const float* __restrict__ x,
                                             const float* __restrict__ w_df,
                                             const float* __restrict__ w_tm,
                                             const float* __restrict__ w_tr,
                                             unsigned short* __restrict__ xt,
                                             unsigned short* __restrict__ wfrag,
                                             unsigned short* __restrict__ w6p) {
  const int b = blockIdx.x;
  const int tid = threadIdx.x;
  if (b < 576) {
    __shared__ unsigned short tile[64][130];
    const int pt = b % 144;          // 144 p-tiles of 64
    const int ch = (b / 144) & 1;    // 2 c-halves of 128
    const int n  = b / 288;
    const int p0 = pt * 64, c0 = ch * 128;
    const float* xp = x + (size_t)n * C_ * HW_;
    unsigned short* xtp = xt + (size_t)n * C_ * HW_;
    const int tx = tid & 15, ty = tid >> 4;  // 16 p-chunks x 16 c-rows
#pragma unroll
    for (int pass = 0; pass < 8; pass++) {
      const int c = pass * 16 + ty;
      const f32x4 v = *(const f32x4*)(xp + (size_t)(c0 + c) * HW_ + p0 + tx * 4);
#pragma unroll
      for (int i = 0; i < 4; i++) tile[tx * 4 + i][c] = f2h(v[i]);
    }
    __syncthreads();
    const int l32 = tid & 31, pr = tid >> 5;  // 32 c-chunks x 8 p-rows
#pragma unroll
    for (int pass = 0; pass < 8; pass++) {
      const int p = pass * 8 + pr;
      us4 v;
#pragma unroll
      for (int i = 0; i < 4; i++) v[i] = tile[p][l32 * 4 + i];
      *(us4*)(xtp + (size_t)(p0 + p) * C_ + c0 + l32 * 4) = v;
    }
  } else if (b < 864) {
    const int base = (b - 576) * 2048 + tid * 8;  // < 589824
    const int l  = (base >> 3) & 63;
    const int g  = (base >> 9) & 15;
    const int ks = (base >> 13) & 7;
    const int t  = base >> 16;
    const int o  = g * 16 + (l & 15);
    const int c  = ks * 32 + (l >> 4) * 8;
    us8 res;
#pragma unroll
    for (int j = 0; j < 8; j++) res[j] = f2h(w_df[(size_t)(o * 256 + c + j) * 9 + t]);
    *(us8*)(wfrag + base) = res;
  } else {
    int idx = (b - 864) * 256 + tid;   // < 9*16*256 = 36864
    int t = idx >> 12;
    int r = idx & 4095;
    int j = r >> 8;
    int c = r & 255;
    float v = 0.f;
    if (j < 4) v = w_tm[(size_t)(j * C_ + c) * 9 + t];
    else if (j < 6) v = w_tr[(size_t)((j - 4) * C_ + c) * 9 + t];
    w6p[idx] = f2h(v);
  }
}

// ---------------- Kernel 2: FUSED offsets + sample + GEMM + BN + res + ReLU.
// v6 = v3 structure (the best measured: 32m x 256o, 512 thr, grid 576,
// wave-tile 32m x 32o, ONE barrier/tap) with two work-removal changes:
//  (a) fp16 pipeline: lerp is pure v_pk_fma_f16 on loaded bits (4 ops/pair
//      vs ~16 for bf16 unpack->f32->repack); MFMA 16x16x32_f16 (same rate).
//      Evidence: kernel is per-CU THROUGHPUT-bound (occupancy 18->36% left
//      time flat/worse in r1-r4), so cut work, don't add waves.
//  (b) launch_bounds(512,3): VGPR cap 85. m69 law: 65..128 VGPR = same
//      4 waves/SIMD (2 blocks/CU) as 64, but v3's exact-64 cap caused ~3MB
//      scratch writes (WRITE 21.9 vs 18.4MB true output). Spill-free now.
__global__ __launch_bounds__(512, 3) void k_fused(const unsigned short* __restrict__ xt,
                                                  const unsigned short* __restrict__ Wfrag,
                                                  const unsigned short* __restrict__ w6p,
                                                  const float* __restrict__ b_tm,
                                                  const float* __restrict__ b_tr,
                                                  const float* __restrict__ xres,
                                                  const float* __restrict__ gamma,
                                                  const float* __restrict__ beta,
                                                  const float* __restrict__ mean,
                                                  const float* __restrict__ var,
                                                  float* __restrict__ out) {
  __shared__ unsigned short As[2][32 * 256] __attribute__((aligned(16)));  // 32KB
  __shared__ float sred[8][16][8];
  __shared__ float coords_s[32][9][2];
  const int tid = threadIdx.x;
  const int wave = tid >> 6, lane = tid & 63;
  const int row = lane & 15, quad = lane >> 4;
  const int bm = (blockIdx.x & 7) * 72 + (blockIdx.x >> 3);  // XCD m-band swizzle
  const int m0 = bm * 32;
  const int n = m0 / HW_;   // 32 | 9216: tile never crosses n
  const int sr = tid >> 4;  // staging row 0..31 (one row per thread)
  const int cg = tid & 15;  // staging 16-channel group

  // ---- Prologue: offset conv for the 32-m strip ----
  // waves 0-3 -> rows 0..15, waves 4-7 -> rows 16..31; each wave a 64-ch quarter.
  {
    const int hw0 = m0 - n * HW_;
    const int h = hw0 / W_;
    const int w0 = hw0 - h * W_;  // multiple of 32 (32 | 96)
    const int rh = wave >> 2;     // row half
    const int cq = (wave & 3) * 64;
    f32x4 oacc = {0.f, 0.f, 0.f, 0.f};
    const f16x8 zero8 = {};
#pragma unroll
    for (int t = 0; t < 9; t++) {
      const int ty = t / 3, tx = t % 3;
      const int y = h + ty - 1;
      if (y < 0 || y >= H_) continue;  // wave-uniform
      const int xx = w0 + rh * 16 + row + tx - 1;
      const bool valid = (xx >= 0) && (xx < W_);
      const int xc = min(max(xx, 0), W_ - 1);
      const unsigned short* arow =
          xt + (size_t)((n * H_ + y) * W_ + xc) * C_ + cq + quad * 8;
      const unsigned short* brow =
          w6p + (size_t)(t * 16 + row) * C_ + cq + quad * 8;
#pragma unroll
      for (int ks = 0; ks < 2; ks++) {
        f16x8 av = *(const f16x8*)(const void*)(arow + ks * 32);
        if (!valid) av = zero8;
        f16x8 bv = *(const f16x8*)(const void*)(brow + ks * 32);
        oacc = __builtin_amdgcn_mfma_f32_16x16x32_f16(av, bv, oacc, 0, 0, 0);
      }
    }
    if (row < 6) {
#pragma unroll
      for (int r = 0; r < 4; r++) sred[wave][quad * 4 + r][row] = oacc[r];
    }
  }
  __syncthreads();
  if (wave < 2 && lane < 16) {
    const int rg = wave * 16 + lane;  // global row 0..31
    const int hwm = m0 + rg - n * HW_;
    const int h = hwm / W_, w = hwm - h * W_;
    float a[6];
#pragma unroll
    for (int j = 0; j < 6; j++)
      a[j] = sred[wave * 4 + 0][lane][j] + sred[wave * 4 + 1][lane][j] +
             sred[wave * 4 + 2][lane][j] + sred[wave * 4 + 3][lane][j];
    const float tm0 = a[0] + b_tm[0];
    const float tm1 = a[1] + b_tm[1];
    const float tm2 = a[2] + b_tm[2];
    const float tm3 = a[3] + b_tm[3];
    const float tr0 = a[4] + b_tr[0];
    const float tr1 = a[5] + b_tr[1];
#pragma unroll
    for (int t = 0; t < 9; t++) {
      const float ry = (float)(t / 3) - 1.f;
      const float rx = (float)(t % 3) - 1.f;
      coords_s[rg][t][0] = (float)h + tr0 + tm0 * ry + tm1 * rx;
      coords_s[rg][t][1] = (float)w + tr1 + tm2 * ry + tm3 * rx;
    }
  }
  __syncthreads();

  // ---- Main loop over 9 taps ----
  f32x4 acc0[2] = {}, acc1[2] = {};
  f16x2 cwh0, cwh1, cwh2, cwh3;  // packed fp16 bilinear weights
  int cb[4];
  us8 u0[4], u1[4];  // corner data for row sr, channels cg*16..+7 and +8..+15

#define PREP1(TAP)                                                             \
  {                                                                            \
    const float py = coords_s[sr][TAP][0];                                     \
    const float px = coords_s[sr][TAP][1];                                     \
    const float fy = floorf(py), fx = floorf(px);                              \
    const float wy = py - fy, wx = px - fx;                                    \
    const int y0 = (int)fy, x0 = (int)fx;                                      \
    const int y1 = y0 + 1, x1 = x0 + 1;                                        \
    const float vy0 = (y0 >= 0 && y0 < H_) ? 1.f : 0.f;                        \
    const float vy1 = (y1 >= 0 && y1 < H_) ? 1.f : 0.f;                        \
    const float vx0 = (x0 >= 0 && x0 < W_) ? 1.f : 0.f;                        \
    const float vx1 = (x1 >= 0 && x1 < W_) ? 1.f : 0.f;                        \
    const float c0f = (1.f - wy) * (1.f - wx) * vy0 * vx0;                     \
    const float c1f = (1.f - wy) * wx * vy0 * vx1;                             \
    const float c2f = wy * (1.f - wx) * vy1 * vx0;                             \
    const float c3f = wy * wx * vy1 * vx1;                                     \
    const _Float16 h0 = (_Float16)c0f, h1 = (_Float16)c1f;                     \
    const _Float16 h2 = (_Float16)c2f, h3 = (_Float16)c3f;                     \
    cwh0 = (f16x2){h0, h0}; cwh1 = (f16x2){h1, h1};                            \
    cwh2 = (f16x2){h2, h2}; cwh3 = (f16x2){h3, h3};                            \
    const int cy0 = min(max(y0, 0), H_ - 1), cy1 = min(max(y1, 0), H_ - 1);    \
    const int cx0 = min(max(x0, 0), W_ - 1), cx1 = min(max(x1, 0), W_ - 1);    \
    cb[0] = ((n * H_ + cy0) * W_ + cx0) * C_;                                  \
    cb[1] = ((n * H_ + cy0) * W_ + cx1) * C_;                                  \
    cb[2] = ((n * H_ + cy1) * W_ + cx0) * C_;                                  \
    cb[3] = ((n * H_ + cy1) * W_ + cx1) * C_;                                  \
  }

#define LOADC1()                                                               \
  {                                                                            \
    const int cc = cg * 16;                                                    \
    u0[0] = *(const us8*)(xt + cb[0] + cc); u1[0] = *(const us8*)(xt + cb[0] + cc + 8); \
    u0[1] = *(const us8*)(xt + cb[1] + cc); u1[1] = *(const us8*)(xt + cb[1] + cc + 8); \
    u0[2] = *(const us8*)(xt + cb[2] + cc); u1[2] = *(const us8*)(xt + cb[2] + cc + 8); \
    u0[3] = *(const us8*)(xt + cb[3] + cc); u1[3] = *(const us8*)(xt + cb[3] + cc + 8); \
  }

  // packed fp16 lerp of one us8 (4 f16-pairs): 4 v_pk_fma_f16 per pair.
#define LERP8V(DST, U)                                                         \
  {                                                                            \
    const f16x2* p0 = (const f16x2*)&U[0];                                     \
    const f16x2* p1 = (const f16x2*)&U[1];                                     \
    const f16x2* p2 = (const f16x2*)&U[2];                                     \
    const f16x2* p3 = (const f16x2*)&U[3];                                     \
    f16x2* d = (f16x2*)&DST;                                                   \
    _Pragma("unroll")                                                          \
    for (int p = 0; p < 4; p++) {                                              \
      f16x2 r = p0[p] * cwh0;                                                  \
      r = p1[p] * cwh1 + r;                                                    \
      r = p2[p] * cwh2 + r;                                                    \
      r = p3[p] * cwh3 + r;                                                    \
      d[p] = r;                                                                \
    }                                                                          \
  }

  PREP1(0);
  LOADC1();

  for (int tap = 0; tap < 9; tap++) {
    unsigned short* __restrict__ asb = As[tap & 1];

    // bv loads issued BEFORE the barrier: the s_barrier vmcnt drain overlaps
    // their L2 latency with other waves' lerp.
    const unsigned short* wfTap =
        Wfrag + (size_t)(tap * 8) * 8192 + wave * 1024 + lane * 8;
    f16x8 bv[2];
#pragma unroll
    for (int ot = 0; ot < 2; ot++) bv[ot] = *(const f16x8*)(const void*)(wfTap + ot * 512);

    // lerp row sr into As[buf] (swizzled slots: slot = (q&24)|((q^sr)&7);
    // (r+16)&7 == r&7 so the read side uses the same slot for row and row+16)
    {
      const int q0 = cg * 2, q1 = cg * 2 + 1;
      const int s0 = (q0 & 24) | ((q0 ^ sr) & 7);
      const int s1 = (q1 & 24) | ((q1 ^ sr) & 7);
      us8 r0, r1;
      LERP8V(r0, u0);
      LERP8V(r1, u1);
      *(us8*)(void*)&asb[sr * 256 + s0 * 8] = r0;
      *(us8*)(void*)&asb[sr * 256 + s1 * 8] = r1;
    }

    __syncthreads();  // ONE barrier per tap

    if (tap < 8) {  // corner prefetch for tap+1, overlapped with the bn stream
      PREP1(tap + 1);
      LOADC1();
    }

#pragma unroll
    for (int ks = 0; ks < 8; ks++) {
      const int q = ks * 4 + quad;
      const int slot = (q & 24) | ((q ^ row) & 7);
      const f16x8 av0 = *(const f16x8*)(const void*)&asb[row * 256 + slot * 8];
      const f16x8 av1 = *(const f16x8*)(const void*)&asb[(row + 16) * 256 + slot * 8];
      f16x8 bn[2];
      if (ks < 7) {
        const unsigned short* wfn = wfTap + (size_t)(ks + 1) * 8192;
#pragma unroll
        for (int ot = 0; ot < 2; ot++) bn[ot] = *(const f16x8*)(const void*)(wfn + ot * 512);
      }
#pragma unroll
      for (int ot = 0; ot < 2; ot++)
        acc0[ot] = __builtin_amdgcn_mfma_f32_16x16x32_f16(av0, bv[ot], acc0[ot], 0, 0, 0);
#pragma unroll
      for (int ot = 0; ot < 2; ot++)
        acc1[ot] = __builtin_amdgcn_mfma_f32_16x16x32_f16(av1, bv[ot], acc1[ot], 0, 0, 0);
      if (ks < 7) {
#pragma unroll
        for (int ot = 0; ot < 2; ot++) bv[ot] = bn[ot];
      }
    }
    // NO trailing barrier: As double-buffered; next write to As[tap&1] happens
    // after barrier(tap+1), which orders all reads of As[tap&1].
  }

  // ---- Epilogue: BN + residual + ReLU, float4 rows (both m-halves) ----
  const int hwb = m0 - n * HW_ + quad * 4;
#pragma unroll
  for (int ot = 0; ot < 2; ot++) {
    const int o = wave * 32 + ot * 16 + row;
    const float sc = rsqrtf(var[o] + 1e-5f) * gamma[o];
    const float bi = beta[o] - mean[o] * sc;
    const size_t ob0 = (size_t)(n * O_ + o) * HW_ + hwb;
    f32x4 rv = *(const f32x4*)(xres + ob0);
    f32x4 ov;
#pragma unroll
    for (int r = 0; r < 4; r++) ov[r] = fmaxf(acc0[ot][r] * sc + bi + rv[r], 0.f);
    *(f32x4*)(out + ob0) = ov;
    const size_t ob1 = ob0 + 16;  // rows 16..31, same h-strip
    rv = *(const f32x4*)(xres + ob1);
#pragma unroll
    for (int r = 0; r < 4; r++) ov[r] = fmaxf(acc1[ot][r] * sc + bi + rv[r], 0.f);
    *(f32x4*)(out + ob1) = ov;
  }
}

extern "C" void kernel_launch(void* const* d_in, const int* in_sizes, int n_in,
                              void* d_out, int out_size, void* d_ws, size_t ws_size,
                              hipStream_t stream) {
  const float* x     = (const float*)d_in[0];
  const float* w_tm  = (const float*)d_in[2];
  const float* b_tm  = (const float*)d_in[3];
  const float* w_tr  = (const float*)d_in[4];
  const float* b_tr  = (const float*)d_in[5];
  const float* w_df  = (const float*)d_in[6];
  const float* gamma = (const float*)d_in[7];
  const float* beta  = (const float*)d_in[8];
  const float* mean  = (const float*)d_in[9];
  const float* var   = (const float*)d_in[10];
  float* out = (float*)d_out;

  char* ws = (char*)d_ws;
  unsigned short* xt    = (unsigned short*)(ws);                       //  9,437,184 B
  unsigned short* wfrag = (unsigned short*)(ws + 9437184);             //  1,179,648 B
  unsigned short* w6p   = (unsigned short*)(ws + 9437184 + 1179648);   //     73,728 B

  k_pre<<<1008, 256, 0, stream>>>(x, w_df, w_tm, w_tr, xt, wfrag, w6p);
  k_fused<<<576, 512, 0, stream>>>(xt, wfrag, w6p, b_tm, b_tr, x,
                                   gamma, beta, mean, var, out);
}

// Round 6
// 182.908 us; speedup vs baseline: 1.2474x; 1.0072x over previous
//
#include <hip/hip_runtime.h>
#include <stdint.h>

#define H_ 96
#define W_ 96
#define C_ 256
#define O_ 256
#define N_ 2
#define HW_ (H_*W_)          // 9216
#define M_ (N_*HW_)          // 18432
#define GK 2304              // C_*9

typedef _Float16 f16x8 __attribute__((ext_vector_type(8)));
typedef _Float16 f16x2 __attribute__((ext_vector_type(2)));
typedef float f32x4 __attribute__((ext_vector_type(4)));
typedef unsigned short us4 __attribute__((ext_vector_type(4)));
typedef unsigned short us8 __attribute__((ext_vector_type(8)));

__device__ __forceinline__ unsigned short f2h(float f) {
  union { _Float16 h; unsigned short u; } v;
  v.h = (_Float16)f;
  return v.u;
}

// ---------------- Kernel 1: combined prep (fp16), unchanged from round 5.
__global__ __launch_bounds__(256) void k_pre(const float* __restrict__ x,
                                             const float* __restrict__ w_df,
                                             const float* __restrict__ w_tm,
                                             const float* __restrict__ w_tr,
                                             unsigned short* __restrict__ xt,
                                             unsigned short* __restrict__ wfrag,
                                             unsigned short* __restrict__ w6p) {
  const int b = blockIdx.x;
  const int tid = threadIdx.x;
  if (b < 576) {
    __shared__ unsigned short tile[64][130];
    const int pt = b % 144;          // 144 p-tiles of 64
    const int ch = (b / 144) & 1;    // 2 c-halves of 128
    const int n  = b / 288;
    const int p0 = pt * 64, c0 = ch * 128;
    const float* xp = x + (size_t)n * C_ * HW_;
    unsigned short* xtp = xt + (size_t)n * C_ * HW_;
    const int tx = tid & 15, ty = tid >> 4;  // 16 p-chunks x 16 c-rows
#pragma unroll
    for (int pass = 0; pass < 8; pass++) {
      const int c = pass * 16 + ty;
      const f32x4 v = *(const f32x4*)(xp + (size_t)(c0 + c) * HW_ + p0 + tx * 4);
#pragma unroll
      for (int i = 0; i < 4; i++) tile[tx * 4 + i][c] = f2h(v[i]);
    }
    __syncthreads();
    const int l32 = tid & 31, pr = tid >> 5;  // 32 c-chunks x 8 p-rows
#pragma unroll
    for (int pass = 0; pass < 8; pass++) {
      const int p = pass * 8 + pr;
      us4 v;
#pragma unroll
      for (int i = 0; i < 4; i++) v[i] = tile[p][l32 * 4 + i];
      *(us4*)(xtp + (size_t)(p0 + p) * C_ + c0 + l32 * 4) = v;
    }
  } else if (b < 864) {
    const int base = (b - 576) * 2048 + tid * 8;  // < 589824
    const int l  = (base >> 3) & 63;
    const int g  = (base >> 9) & 15;
    const int ks = (base >> 13) & 7;
    const int t  = base >> 16;
    const int o  = g * 16 + (l & 15);
    const int c  = ks * 32 + (l >> 4) * 8;
    us8 res;
#pragma unroll
    for (int j = 0; j < 8; j++) res[j] = f2h(w_df[(size_t)(o * 256 + c + j) * 9 + t]);
    *(us8*)(wfrag + base) = res;
  } else {
    int idx = (b - 864) * 256 + tid;   // < 9*16*256 = 36864
    int t = idx >> 12;
    int r = idx & 4095;
    int j = r >> 8;
    int c = r & 255;
    float v = 0.f;
    if (j < 4) v = w_tm[(size_t)(j * C_ + c) * 9 + t];
    else if (j < 6) v = w_tr[(size_t)((j - 4) * C_ + c) * 9 + t];
    w6p[idx] = f2h(v);
  }
}

// ---------------- Kernel 2: FUSED offsets + sample + GEMM + BN + res + ReLU.
// v7 = v6 + REAL prefetch. Diagnosis: v6's VGPR=44 proves the compiler SANK
// the corner/bn "prefetch" loads to their uses (8 corner us8 alone = 32
// VGPR; 44 total means nothing was held) -> every tap paid raw L2 latency
// at the lerp and at each ks step. Fix:
//  (a) sched_barrier(0) pins: pre-barrier B loads issue BEFORE the lerp
//      (latency hidden under lerp; barrier vmcnt(0) drain finishes them),
//      corner loads issue right after the barrier (can't sink to next lerp).
//  (b) depth-2 rolling B pipeline: hold 4 frags (ks, ks+1); at step ks
//      issue ks+2's pair. Static slot rotation, fully unrolled.
//  (c) launch_bounds(512,2): VGPR cap 128 -- safety vs the 85-cap edge.
//      Occupancy proven irrelevant (r1-r5: 18-36% all ~86-96us); spill is
//      catastrophic (r3). Expect VGPR ~80-90, WRITE_SIZE == 18.43MB.
__global__ __launch_bounds__(512, 2) void k_fused(const unsigned short* __restrict__ xt,
                                                  const unsigned short* __restrict__ Wfrag,
                                                  const unsigned short* __restrict__ w6p,
                                                  const float* __restrict__ b_tm,
                                                  const float* __restrict__ b_tr,
                                                  const float* __restrict__ xres,
                                                  const float* __restrict__ gamma,
                                                  const float* __restrict__ beta,
                                                  const float* __restrict__ mean,
                                                  const float* __restrict__ var,
                                                  float* __restrict__ out) {
  __shared__ unsigned short As[2][32 * 256] __attribute__((aligned(16)));  // 32KB
  __shared__ float sred[8][16][8];
  __shared__ float coords_s[32][9][2];
  const int tid = threadIdx.x;
  const int wave = tid >> 6, lane = tid & 63;
  const int row = lane & 15, quad = lane >> 4;
  const int bm = (blockIdx.x & 7) * 72 + (blockIdx.x >> 3);  // XCD m-band swizzle
  const int m0 = bm * 32;
  const int n = m0 / HW_;   // 32 | 9216: tile never crosses n
  const int sr = tid >> 4;  // staging row 0..31 (one row per thread)
  const int cg = tid & 15;  // staging 16-channel group

  // ---- Prologue: offset conv for the 32-m strip ----
  {
    const int hw0 = m0 - n * HW_;
    const int h = hw0 / W_;
    const int w0 = hw0 - h * W_;  // multiple of 32 (32 | 96)
    const int rh = wave >> 2;     // row half
    const int cq = (wave & 3) * 64;
    f32x4 oacc = {0.f, 0.f, 0.f, 0.f};
    const f16x8 zero8 = {};
#pragma unroll
    for (int t = 0; t < 9; t++) {
      const int ty = t / 3, tx = t % 3;
      const int y = h + ty - 1;
      if (y < 0 || y >= H_) continue;  // wave-uniform
      const int xx = w0 + rh * 16 + row + tx - 1;
      const bool valid = (xx >= 0) && (xx < W_);
      const int xc = min(max(xx, 0), W_ - 1);
      const unsigned short* arow =
          xt + (size_t)((n * H_ + y) * W_ + xc) * C_ + cq + quad * 8;
      const unsigned short* brow =
          w6p + (size_t)(t * 16 + row) * C_ + cq + quad * 8;
#pragma unroll
      for (int ks = 0; ks < 2; ks++) {
        f16x8 av = *(const f16x8*)(const void*)(arow + ks * 32);
        if (!valid) av = zero8;
        f16x8 bv = *(const f16x8*)(const void*)(brow + ks * 32);
        oacc = __builtin_amdgcn_mfma_f32_16x16x32_f16(av, bv, oacc, 0, 0, 0);
      }
    }
    if (row < 6) {
#pragma unroll
      for (int r = 0; r < 4; r++) sred[wave][quad * 4 + r][row] = oacc[r];
    }
  }
  __syncthreads();
  if (wave < 2 && lane < 16) {
    const int rg = wave * 16 + lane;  // global row 0..31
    const int hwm = m0 + rg - n * HW_;
    const int h = hwm / W_, w = hwm - h * W_;
    float a[6];
#pragma unroll
    for (int j = 0; j < 6; j++)
      a[j] = sred[wave * 4 + 0][lane][j] + sred[wave * 4 + 1][lane][j] +
             sred[wave * 4 + 2][lane][j] + sred[wave * 4 + 3][lane][j];
    const float tm0 = a[0] + b_tm[0];
    const float tm1 = a[1] + b_tm[1];
    const float tm2 = a[2] + b_tm[2];
    const float tm3 = a[3] + b_tm[3];
    const float tr0 = a[4] + b_tr[0];
    const float tr1 = a[5] + b_tr[1];
#pragma unroll
    for (int t = 0; t < 9; t++) {
      const float ry = (float)(t / 3) - 1.f;
      const float rx = (float)(t % 3) - 1.f;
      coords_s[rg][t][0] = (float)h + tr0 + tm0 * ry + tm1 * rx;
      coords_s[rg][t][1] = (float)w + tr1 + tm2 * ry + tm3 * rx;
    }
  }
  __syncthreads();

  // ---- Main loop over 9 taps ----
  f32x4 acc0[2] = {}, acc1[2] = {};
  f16x2 cwh0, cwh1, cwh2, cwh3;  // packed fp16 bilinear weights
  int cb[4];
  us8 u0[4], u1[4];  // corner data for row sr, channels cg*16..+7 and +8..+15

#define PREP1(TAP)                                                             \
  {                                                                            \
    const float py = coords_s[sr][TAP][0];                                     \
    const float px = coords_s[sr][TAP][1];                                     \
    const float fy = floorf(py), fx = floorf(px);                              \
    const float wy = py - fy, wx = px - fx;                                    \
    const int y0 = (int)fy, x0 = (int)fx;                                      \
    const int y1 = y0 + 1, x1 = x0 + 1;                                        \
    const float vy0 = (y0 >= 0 && y0 < H_) ? 1.f : 0.f;                        \
    const float vy1 = (y1 >= 0 && y1 < H_) ? 1.f : 0.f;                        \
    const float vx0 = (x0 >= 0 && x0 < W_) ? 1.f : 0.f;                        \
    const float vx1 = (x1 >= 0 && x1 < W_) ? 1.f : 0.f;                        \
    const float c0f = (1.f - wy) * (1.f - wx) * vy0 * vx0;                     \
    const float c1f = (1.f - wy) * wx * vy0 * vx1;                             \
    const float c2f = wy * (1.f - wx) * vy1 * vx0;                             \
    const float c3f = wy * wx * vy1 * vx1;                                     \
    const _Float16 h0 = (_Float16)c0f, h1 = (_Float16)c1f;                     \
    const _Float16 h2 = (_Float16)c2f, h3 = (_Float16)c3f;                     \
    cwh0 = (f16x2){h0, h0}; cwh1 = (f16x2){h1, h1};                            \
    cwh2 = (f16x2){h2, h2}; cwh3 = (f16x2){h3, h3};                            \
    const int cy0 = min(max(y0, 0), H_ - 1), cy1 = min(max(y1, 0), H_ - 1);    \
    const int cx0 = min(max(x0, 0), W_ - 1), cx1 = min(max(x1, 0), W_ - 1);    \
    cb[0] = ((n * H_ + cy0) * W_ + cx0) * C_;                                  \
    cb[1] = ((n * H_ + cy0) * W_ + cx1) * C_;                                  \
    cb[2] = ((n * H_ + cy1) * W_ + cx0) * C_;                                  \
    cb[3] = ((n * H_ + cy1) * W_ + cx1) * C_;                                  \
  }

#define LOADC1()                                                               \
  {                                                                            \
    const int cc = cg * 16;                                                    \
    u0[0] = *(const us8*)(xt + cb[0] + cc); u1[0] = *(const us8*)(xt + cb[0] + cc + 8); \
    u0[1] = *(const us8*)(xt + cb[1] + cc); u1[1] = *(const us8*)(xt + cb[1] + cc + 8); \
    u0[2] = *(const us8*)(xt + cb[2] + cc); u1[2] = *(const us8*)(xt + cb[2] + cc + 8); \
    u0[3] = *(const us8*)(xt + cb[3] + cc); u1[3] = *(const us8*)(xt + cb[3] + cc + 8); \
  }

  // packed fp16 lerp of one us8 (4 f16-pairs): 4 v_pk_fma_f16 per pair.
#define LERP8V(DST, U)                                                         \
  {                                                                            \
    const f16x2* p0 = (const f16x2*)&U[0];                                     \
    const f16x2* p1 = (const f16x2*)&U[1];                                     \
    const f16x2* p2 = (const f16x2*)&U[2];                                     \
    const f16x2* p3 = (const f16x2*)&U[3];                                     \
    f16x2* d = (f16x2*)&DST;                                                   \
    _Pragma("unroll")                                                          \
    for (int p = 0; p < 4; p++) {                                              \
      f16x2 r = p0[p] * cwh0;                                                  \
      r = p1[p] * cwh1 + r;                                                    \
      r = p2[p] * cwh2 + r;                                                    \
      r = p3[p] * cwh3 + r;                                                    \
      d[p] = r;                                                                \
    }                                                                          \
  }

  // One ks step: use fragment pair (Bx,By); issue loads for step KS+2 into
  // the same slots (SSA rename handles WAR). Fully static indices.
#define KSTEP(KS, Bx, By)                                                      \
  {                                                                            \
    const int q = (KS) * 4 + quad;                                             \
    const int slt = (q & 24) | ((q ^ row) & 7);                                \
    const f16x8 av0 = *(const f16x8*)(const void*)&asb[row * 256 + slt * 8];   \
    const f16x8 av1 = *(const f16x8*)(const void*)&asb[(row + 16) * 256 + slt * 8]; \
    f16x8 nx, ny;                                                              \
    if ((KS) < 6) {                                                            \
      const unsigned short* wfn = wfTap + (size_t)((KS) + 2) * 8192;           \
      nx = *(const f16x8*)(const void*)(wfn);                                  \
      ny = *(const f16x8*)(const void*)(wfn + 512);                            \
    }                                                                          \
    acc0[0] = __builtin_amdgcn_mfma_f32_16x16x32_f16(av0, Bx, acc0[0], 0, 0, 0); \
    acc0[1] = __builtin_amdgcn_mfma_f32_16x16x32_f16(av0, By, acc0[1], 0, 0, 0); \
    acc1[0] = __builtin_amdgcn_mfma_f32_16x16x32_f16(av1, Bx, acc1[0], 0, 0, 0); \
    acc1[1] = __builtin_amdgcn_mfma_f32_16x16x32_f16(av1, By, acc1[1], 0, 0, 0); \
    if ((KS) < 6) { Bx = nx; By = ny; }                                        \
  }

  PREP1(0);
  LOADC1();

  for (int tap = 0; tap < 9; tap++) {
    unsigned short* __restrict__ asb = As[tap & 1];
    const unsigned short* wfTap =
        Wfrag + (size_t)(tap * 8) * 8192 + wave * 1024 + lane * 8;

    // Pre-barrier B prefetch: frags for ks0,ks1 (4 frags, 16 VGPR), issued
    // BEFORE the lerp so L2 latency hides under lerp VALU; the barrier's
    // vmcnt(0) drain completes them for free.
    f16x8 B0 = *(const f16x8*)(const void*)(wfTap);
    f16x8 B1 = *(const f16x8*)(const void*)(wfTap + 512);
    f16x8 B2 = *(const f16x8*)(const void*)(wfTap + 8192);
    f16x8 B3 = *(const f16x8*)(const void*)(wfTap + 8704);
    __builtin_amdgcn_sched_barrier(0);  // pin: B loads issue before the lerp

    // lerp row sr into As[buf] (swizzled slots: slot = (q&24)|((q^sr)&7))
    {
      const int q0 = cg * 2, q1 = cg * 2 + 1;
      const int s0 = (q0 & 24) | ((q0 ^ sr) & 7);
      const int s1 = (q1 & 24) | ((q1 ^ sr) & 7);
      us8 r0, r1;
      LERP8V(r0, u0);
      LERP8V(r1, u1);
      *(us8*)(void*)&asb[sr * 256 + s0 * 8] = r0;
      *(us8*)(void*)&asb[sr * 256 + s1 * 8] = r1;
    }

    __syncthreads();  // ONE barrier per tap (drains all pre-barrier loads)

    if (tap < 8) {  // corner prefetch for tap+1: pinned here, consumed at
      PREP1(tap + 1);  // next tap's lerp (slack = whole ks loop)
      LOADC1();
    }
    __builtin_amdgcn_sched_barrier(0);  // pin: corner loads cannot sink

    KSTEP(0, B0, B1)
    KSTEP(1, B2, B3)
    KSTEP(2, B0, B1)
    KSTEP(3, B2, B3)
    KSTEP(4, B0, B1)
    KSTEP(5, B2, B3)
    KSTEP(6, B0, B1)
    KSTEP(7, B2, B3)
    // NO trailing barrier: As double-buffered; next write to As[tap&1] happens
    // after barrier(tap+1), which orders all reads of As[tap&1].
  }

  // ---- Epilogue: BN + residual + ReLU, float4 rows (both m-halves) ----
  const int hwb = m0 - n * HW_ + quad * 4;
#pragma unroll
  for (int ot = 0; ot < 2; ot++) {
    const int o = wave * 32 + ot * 16 + row;
    const float sc = rsqrtf(var[o] + 1e-5f) * gamma[o];
    const float bi = beta[o] - mean[o] * sc;
    const size_t ob0 = (size_t)(n * O_ + o) * HW_ + hwb;
    f32x4 rv = *(const f32x4*)(xres + ob0);
    f32x4 ov;
#pragma unroll
    for (int r = 0; r < 4; r++) ov[r] = fmaxf(acc0[ot][r] * sc + bi + rv[r], 0.f);
    *(f32x4*)(out + ob0) = ov;
    const size_t ob1 = ob0 + 16;  // rows 16..31, same h-strip
    rv = *(const f32x4*)(xres + ob1);
#pragma unroll
    for (int r = 0; r < 4; r++) ov[r] = fmaxf(acc1[ot][r] * sc + bi + rv[r], 0.f);
    *(f32x4*)(out + ob1) = ov;
  }
}

extern "C" void kernel_launch(void* const* d_in, const int* in_sizes, int n_in,
                              void* d_out, int out_size, void* d_ws, size_t ws_size,
                              hipStream_t stream) {
  const float* x     = (const float*)d_in[0];
  const float* w_tm  = (const float*)d_in[2];
  const float* b_tm  = (const float*)d_in[3];
  const float* w_tr  = (const float*)d_in[4];
  const float* b_tr  = (const float*)d_in[5];
  const float* w_df  = (const float*)d_in[6];
  const float* gamma = (const float*)d_in[7];
  const float* beta  = (const float*)d_in[8];
  const float* mean  = (const float*)d_in[9];
  const float* var   = (const float*)d_in[10];
  float* out = (float*)d_out;

  char* ws = (char*)d_ws;
  unsigned short* xt    = (unsigned short*)(ws);                       //  9,437,184 B
  unsigned short* wfrag = (unsigned short*)(ws + 9437184);             //  1,179,648 B
  unsigned short* w6p   = (unsigned short*)(ws + 9437184 + 1179648);   //     73,728 B

  k_pre<<<1008, 256, 0, stream>>>(x, w_df, w_tm, w_tr, xt, wfrag, w6p);
  k_fused<<<576, 512, 0, stream>>>(xt, wfrag, w6p, b_tm, b_tr, x,
                                   gamma, beta, mean, var, out);
}

// Round 7
// 176.036 us; speedup vs baseline: 1.2961x; 1.0390x over previous
//
#include <hip/hip_runtime.h>
#include <stdint.h>

#define H_ 96
#define W_ 96
#define C_ 256
#define O_ 256
#define N_ 2
#define HW_ (H_*W_)          // 9216
#define M_ (N_*HW_)          // 18432
#define GK 2304              // C_*9

typedef _Float16 f16x8 __attribute__((ext_vector_type(8)));
typedef _Float16 f16x2 __attribute__((ext_vector_type(2)));
typedef float f32x4 __attribute__((ext_vector_type(4)));
typedef unsigned short us4 __attribute__((ext_vector_type(4)));
typedef unsigned short us8 __attribute__((ext_vector_type(8)));

__device__ __forceinline__ unsigned short f2h(float f) {
  union { _Float16 h; unsigned short u; } v;
  v.h = (_Float16)f;
  return v.u;
}
__device__ __forceinline__ f16x2 hpair(float f) {
  const _Float16 h = (_Float16)f;
  return (f16x2){h, h};
}

// ---------------- Kernel 1: combined prep (fp16), unchanged.
__global__ __launch_bounds__(256) void k_pre(const float* __restrict__ x,
                                             const float* __restrict__ w_df,
                                             const float* __restrict__ w_tm,
                                             const float* __restrict__ w_tr,
                                             unsigned short* __restrict__ xt,
                                             unsigned short* __restrict__ wfrag,
                                             unsigned short* __restrict__ w6p) {
  const int b = blockIdx.x;
  const int tid = threadIdx.x;
  if (b < 576) {
    __shared__ unsigned short tile[64][130];
    const int pt = b % 144;          // 144 p-tiles of 64
    const int ch = (b / 144) & 1;    // 2 c-halves of 128
    const int n  = b / 288;
    const int p0 = pt * 64, c0 = ch * 128;
    const float* xp = x + (size_t)n * C_ * HW_;
    unsigned short* xtp = xt + (size_t)n * C_ * HW_;
    const int tx = tid & 15, ty = tid >> 4;  // 16 p-chunks x 16 c-rows
#pragma unroll
    for (int pass = 0; pass < 8; pass++) {
      const int c = pass * 16 + ty;
      const f32x4 v = *(const f32x4*)(xp + (size_t)(c0 + c) * HW_ + p0 + tx * 4);
#pragma unroll
      for (int i = 0; i < 4; i++) tile[tx * 4 + i][c] = f2h(v[i]);
    }
    __syncthreads();
    const int l32 = tid & 31, pr = tid >> 5;  // 32 c-chunks x 8 p-rows
#pragma unroll
    for (int pass = 0; pass < 8; pass++) {
      const int p = pass * 8 + pr;
      us4 v;
#pragma unroll
      for (int i = 0; i < 4; i++) v[i] = tile[p][l32 * 4 + i];
      *(us4*)(xtp + (size_t)(p0 + p) * C_ + c0 + l32 * 4) = v;
    }
  } else if (b < 864) {
    const int base = (b - 576) * 2048 + tid * 8;  // < 589824
    const int l  = (base >> 3) & 63;
    const int g  = (base >> 9) & 15;
    const int ks = (base >> 13) & 7;
    const int t  = base >> 16;
    const int o  = g * 16 + (l & 15);
    const int c  = ks * 32 + (l >> 4) * 8;
    us8 res;
#pragma unroll
    for (int j = 0; j < 8; j++) res[j] = f2h(w_df[(size_t)(o * 256 + c + j) * 9 + t]);
    *(us8*)(wfrag + base) = res;
  } else {
    int idx = (b - 864) * 256 + tid;   // < 9*16*256 = 36864
    int t = idx >> 12;
    int r = idx & 4095;
    int j = r >> 8;
    int c = r & 255;
    float v = 0.f;
    if (j < 4) v = w_tm[(size_t)(j * C_ + c) * 9 + t];
    else if (j < 6) v = w_tr[(size_t)((j - 4) * C_ + c) * 9 + t];
    w6p[idx] = f2h(v);
  }
}

// ---------------- Kernel 2: FUSED offsets + sample + GEMM + BN + res + ReLU.
// v8: STAGE-ALL-9-TAPS, ONE BARRIER. Six rounds proved the per-tap
// barrier structure leaks ~90%: per-tap wall ~10K cyc vs ~700-cyc critical
// path, invariant to occupancy (18-36%), VALU work, and prefetch pins.
// New shape (150KB LDS, 1 block/CU, grid 576, 512 thr / 8 waves):
//   phase 1: lerp all 9 A-tiles into As9[9][32*256] -- no barriers, reg
//            double-buffered depth-2 corner prefetch, sched-fence pinned.
//   ONE __syncthreads().
//   phase 2: flat 72-step GEMM burst: 288 MFMA/wave, B prefetch depth-4
//            (loads live across the whole burst -- no barrier ever drains
//            them), A ds_read depth-1, sched_barrier(0) per step.
// Barriers/block: 11 -> 3 (2 prologue + 1 main).
__global__ __launch_bounds__(512, 2) void k_fused(const unsigned short* __restrict__ xt,
                                                  const unsigned short* __restrict__ Wfrag,
                                                  const unsigned short* __restrict__ w6p,
                                                  const float* __restrict__ b_tm,
                                                  const float* __restrict__ b_tr,
                                                  const float* __restrict__ xres,
                                                  const float* __restrict__ gamma,
                                                  const float* __restrict__ beta,
                                                  const float* __restrict__ mean,
                                                  const float* __restrict__ var,
                                                  float* __restrict__ out) {
  __shared__ unsigned short As9[9][32 * 256] __attribute__((aligned(16)));  // 144KB
  __shared__ float sred[8][16][8];       // 4KB (prologue only)
  __shared__ float coords_s[32][9][2];   // 2.25KB
  const int tid = threadIdx.x;
  const int wave = tid >> 6, lane = tid & 63;
  const int row = lane & 15, quad = lane >> 4;
  const int bm = (blockIdx.x & 7) * 72 + (blockIdx.x >> 3);  // XCD m-band swizzle
  const int m0 = bm * 32;
  const int n = m0 / HW_;   // 32 | 9216: tile never crosses n
  const int sr = tid >> 4;  // staging row 0..31 (one row per thread)
  const int cg = tid & 15;  // staging 16-channel group

  // ---- Prologue: offset conv for the 32-m strip ----
  {
    const int hw0 = m0 - n * HW_;
    const int h = hw0 / W_;
    const int w0 = hw0 - h * W_;  // multiple of 32 (32 | 96)
    const int rh = wave >> 2;     // row half
    const int cq = (wave & 3) * 64;
    f32x4 oacc = {0.f, 0.f, 0.f, 0.f};
    const f16x8 zero8 = {};
#pragma unroll
    for (int t = 0; t < 9; t++) {
      const int ty = t / 3, tx = t % 3;
      const int y = h + ty - 1;
      if (y < 0 || y >= H_) continue;  // wave-uniform
      const int xx = w0 + rh * 16 + row + tx - 1;
      const bool valid = (xx >= 0) && (xx < W_);
      const int xc = min(max(xx, 0), W_ - 1);
      const unsigned short* arow =
          xt + (size_t)((n * H_ + y) * W_ + xc) * C_ + cq + quad * 8;
      const unsigned short* brow =
          w6p + (size_t)(t * 16 + row) * C_ + cq + quad * 8;
#pragma unroll
      for (int ks = 0; ks < 2; ks++) {
        f16x8 av = *(const f16x8*)(const void*)(arow + ks * 32);
        if (!valid) av = zero8;
        f16x8 bv = *(const f16x8*)(const void*)(brow + ks * 32);
        oacc = __builtin_amdgcn_mfma_f32_16x16x32_f16(av, bv, oacc, 0, 0, 0);
      }
    }
    if (row < 6) {
#pragma unroll
      for (int r = 0; r < 4; r++) sred[wave][quad * 4 + r][row] = oacc[r];
    }
  }
  __syncthreads();
  if (wave < 2 && lane < 16) {
    const int rg = wave * 16 + lane;  // global row 0..31
    const int hwm = m0 + rg - n * HW_;
    const int h = hwm / W_, w = hwm - h * W_;
    float a[6];
#pragma unroll
    for (int j = 0; j < 6; j++)
      a[j] = sred[wave * 4 + 0][lane][j] + sred[wave * 4 + 1][lane][j] +
             sred[wave * 4 + 2][lane][j] + sred[wave * 4 + 3][lane][j];
    const float tm0 = a[0] + b_tm[0];
    const float tm1 = a[1] + b_tm[1];
    const float tm2 = a[2] + b_tm[2];
    const float tm3 = a[3] + b_tm[3];
    const float tr0 = a[4] + b_tr[0];
    const float tr1 = a[5] + b_tr[1];
#pragma unroll
    for (int t = 0; t < 9; t++) {
      const float ry = (float)(t / 3) - 1.f;
      const float rx = (float)(t % 3) - 1.f;
      coords_s[rg][t][0] = (float)h + tr0 + tm0 * ry + tm1 * rx;
      coords_s[rg][t][1] = (float)w + tr1 + tm2 * ry + tm3 * rx;
    }
  }
  __syncthreads();

  // ================= PHASE 1: stage all 9 taps (no barriers) =================
  f16x2 cwA0, cwA1, cwA2, cwA3, cwB0, cwB1, cwB2, cwB3;
  us8 uA0[4], uA1[4], uB0[4], uB1[4];  // two corner register sets (depth-2)

  // PREP coords + issue corner loads for TAP into register set S
#define PL(TAP, S)                                                             \
  {                                                                            \
    const float py = coords_s[sr][TAP][0];                                     \
    const float px = coords_s[sr][TAP][1];                                     \
    const float fy = floorf(py), fx = floorf(px);                              \
    const float wy = py - fy, wx = px - fx;                                    \
    const int y0 = (int)fy, x0 = (int)fx;                                      \
    const int y1 = y0 + 1, x1 = x0 + 1;                                        \
    const float vy0 = (y0 >= 0 && y0 < H_) ? 1.f : 0.f;                        \
    const float vy1 = (y1 >= 0 && y1 < H_) ? 1.f : 0.f;                        \
    const float vx0 = (x0 >= 0 && x0 < W_) ? 1.f : 0.f;                        \
    const float vx1 = (x1 >= 0 && x1 < W_) ? 1.f : 0.f;                        \
    cw##S##0 = hpair((1.f - wy) * (1.f - wx) * vy0 * vx0);                     \
    cw##S##1 = hpair((1.f - wy) * wx * vy0 * vx1);                             \
    cw##S##2 = hpair(wy * (1.f - wx) * vy1 * vx0);                             \
    cw##S##3 = hpair(wy * wx * vy1 * vx1);                                     \
    const int cy0 = min(max(y0, 0), H_ - 1), cy1 = min(max(y1, 0), H_ - 1);    \
    const int cx0 = min(max(x0, 0), W_ - 1), cx1 = min(max(x1, 0), W_ - 1);    \
    const int b0 = ((n * H_ + cy0) * W_ + cx0) * C_ + cg * 16;                 \
    const int b1 = ((n * H_ + cy0) * W_ + cx1) * C_ + cg * 16;                 \
    const int b2 = ((n * H_ + cy1) * W_ + cx0) * C_ + cg * 16;                 \
    const int b3 = ((n * H_ + cy1) * W_ + cx1) * C_ + cg * 16;                 \
    u##S##0[0] = *(const us8*)(xt + b0); u##S##1[0] = *(const us8*)(xt + b0 + 8); \
    u##S##0[1] = *(const us8*)(xt + b1); u##S##1[1] = *(const us8*)(xt + b1 + 8); \
    u##S##0[2] = *(const us8*)(xt + b2); u##S##1[2] = *(const us8*)(xt + b2 + 8); \
    u##S##0[3] = *(const us8*)(xt + b3); u##S##1[3] = *(const us8*)(xt + b3 + 8); \
  }

  // packed fp16 lerp of 4 corner us8 -> one us8
#define LERPS(DST, U, C0, C1, C2, C3)                                          \
  {                                                                            \
    const f16x2* q0 = (const f16x2*)&U[0];                                     \
    const f16x2* q1 = (const f16x2*)&U[1];                                     \
    const f16x2* q2 = (const f16x2*)&U[2];                                     \
    const f16x2* q3 = (const f16x2*)&U[3];                                     \
    f16x2* d = (f16x2*)&DST;                                                   \
    _Pragma("unroll")                                                          \
    for (int p = 0; p < 4; p++) {                                              \
      f16x2 r = q0[p] * C0;                                                    \
      r = q1[p] * C1 + r;                                                      \
      r = q2[p] * C2 + r;                                                      \
      r = q3[p] * C3 + r;                                                      \
      d[p] = r;                                                                \
    }                                                                          \
  }

  // lerp register set S -> As9[TAP] (swizzled slots: slot=(q&24)|((q^sr)&7))
#define LS(TAP, S)                                                             \
  {                                                                            \
    unsigned short* asb = &As9[TAP][0];                                        \
    const int q0i = cg * 2, q1i = cg * 2 + 1;                                  \
    const int s0 = (q0i & 24) | ((q0i ^ sr) & 7);                              \
    const int s1 = (q1i & 24) | ((q1i ^ sr) & 7);                              \
    us8 r0, r1;                                                                \
    LERPS(r0, u##S##0, cw##S##0, cw##S##1, cw##S##2, cw##S##3);                \
    LERPS(r1, u##S##1, cw##S##0, cw##S##1, cw##S##2, cw##S##3);                \
    *(us8*)(void*)&asb[sr * 256 + s0 * 8] = r0;                                \
    *(us8*)(void*)&asb[sr * 256 + s1 * 8] = r1;                                \
  }

  PL(0, A);
  PL(1, B);
  __builtin_amdgcn_sched_barrier(0);
  LS(0, A); PL(2, A); __builtin_amdgcn_sched_barrier(0);
  LS(1, B); PL(3, B); __builtin_amdgcn_sched_barrier(0);
  LS(2, A); PL(4, A); __builtin_amdgcn_sched_barrier(0);
  LS(3, B); PL(5, B); __builtin_amdgcn_sched_barrier(0);
  LS(4, A); PL(6, A); __builtin_amdgcn_sched_barrier(0);
  LS(5, B); PL(7, B); __builtin_amdgcn_sched_barrier(0);
  LS(6, A); PL(8, A); __builtin_amdgcn_sched_barrier(0);
  LS(7, B);
  LS(8, A);

  __syncthreads();  // THE one barrier: all 9 A-tiles staged.

  // ================= PHASE 2: flat 72-step GEMM burst =================
  f32x4 acc0[2] = {}, acc1[2] = {};
  const unsigned short* wfW = Wfrag + wave * 1024 + lane * 8;

  // B prefetch depth-4: 8 fragments (kk=0..3), 32 VGPR. Loads stay in
  // flight across steps -- no barrier ever drains them.
  f16x8 P0 = *(const f16x8*)(const void*)(wfW + (size_t)0 * 8192);
  f16x8 P1 = *(const f16x8*)(const void*)(wfW + (size_t)0 * 8192 + 512);
  f16x8 P2 = *(const f16x8*)(const void*)(wfW + (size_t)1 * 8192);
  f16x8 P3 = *(const f16x8*)(const void*)(wfW + (size_t)1 * 8192 + 512);
  f16x8 P4 = *(const f16x8*)(const void*)(wfW + (size_t)2 * 8192);
  f16x8 P5 = *(const f16x8*)(const void*)(wfW + (size_t)2 * 8192 + 512);
  f16x8 P6 = *(const f16x8*)(const void*)(wfW + (size_t)3 * 8192);
  f16x8 P7 = *(const f16x8*)(const void*)(wfW + (size_t)3 * 8192 + 512);

  // A ds_read depth-1 pipeline
  f16x8 avc0, avc1;
  {
    const int q = quad;  // kk=0: ks=0 -> q = quad
    const int sl = (q & 24) | ((q ^ row) & 7);
    avc0 = *(const f16x8*)(const void*)&As9[0][row * 256 + sl * 8];
    avc1 = *(const f16x8*)(const void*)&As9[0][(row + 16) * 256 + sl * 8];
  }

  // One GEMM step kk=KK: 4 MFMA on (avc, BX/BY); ds_read av for KK+1;
  // global-load B for KK+4. All indices compile-time (unrolled loop).
#define GS(KK, BX, BY)                                                         \
  {                                                                            \
    f16x8 nx, ny, an0, an1;                                                    \
    if ((KK) < 71) {                                                           \
      const int qn = (((KK) + 1) & 7) * 4 + quad;                              \
      const int sln = (qn & 24) | ((qn ^ row) & 7);                            \
      const unsigned short* ab = &As9[((KK) + 1) >> 3][0];                     \
      an0 = *(const f16x8*)(const void*)&ab[row * 256 + sln * 8];              \
      an1 = *(const f16x8*)(const void*)&ab[(row + 16) * 256 + sln * 8];       \
    }                                                                          \
    if ((KK) < 68) {                                                           \
      const unsigned short* wfn = wfW + (size_t)((KK) + 4) * 8192;             \
      nx = *(const f16x8*)(const void*)(wfn);                                  \
      ny = *(const f16x8*)(const void*)(wfn + 512);                            \
    }                                                                          \
    acc0[0] = __builtin_amdgcn_mfma_f32_16x16x32_f16(avc0, BX, acc0[0], 0, 0, 0); \
    acc0[1] = __builtin_amdgcn_mfma_f32_16x16x32_f16(avc0, BY, acc0[1], 0, 0, 0); \
    acc1[0] = __builtin_amdgcn_mfma_f32_16x16x32_f16(avc1, BX, acc1[0], 0, 0, 0); \
    acc1[1] = __builtin_amdgcn_mfma_f32_16x16x32_f16(avc1, BY, acc1[1], 0, 0, 0); \
    __builtin_amdgcn_sched_barrier(0);                                         \
    if ((KK) < 71) { avc0 = an0; avc1 = an1; }                                 \
    if ((KK) < 68) { BX = nx; BY = ny; }                                       \
  }

#pragma unroll
  for (int kb = 0; kb < 72; kb += 4) {
    GS(kb + 0, P0, P1);
    GS(kb + 1, P2, P3);
    GS(kb + 2, P4, P5);
    GS(kb + 3, P6, P7);
  }

  // ---- Epilogue: BN + residual + ReLU, float4 rows (both m-halves) ----
  const int hwb = m0 - n * HW_ + quad * 4;
#pragma unroll
  for (int ot = 0; ot < 2; ot++) {
    const int o = wave * 32 + ot * 16 + row;
    const float sc = rsqrtf(var[o] + 1e-5f) * gamma[o];
    const float bi = beta[o] - mean[o] * sc;
    const size_t ob0 = (size_t)(n * O_ + o) * HW_ + hwb;
    f32x4 rv = *(const f32x4*)(xres + ob0);
    f32x4 ov;
#pragma unroll
    for (int r = 0; r < 4; r++) ov[r] = fmaxf(acc0[ot][r] * sc + bi + rv[r], 0.f);
    *(f32x4*)(out + ob0) = ov;
    const size_t ob1 = ob0 + 16;  // rows 16..31, same h-strip
    rv = *(const f32x4*)(xres + ob1);
#pragma unroll
    for (int r = 0; r < 4; r++) ov[r] = fmaxf(acc1[ot][r] * sc + bi + rv[r], 0.f);
    *(f32x4*)(out + ob1) = ov;
  }
}

extern "C" void kernel_launch(void* const* d_in, const int* in_sizes, int n_in,
                              void* d_out, int out_size, void* d_ws, size_t ws_size,
                              hipStream_t stream) {
  const float* x     = (const float*)d_in[0];
  const float* w_tm  = (const float*)d_in[2];
  const float* b_tm  = (const float*)d_in[3];
  const float* w_tr  = (const float*)d_in[4];
  const float* b_tr  = (const float*)d_in[5];
  const float* w_df  = (const float*)d_in[6];
  const float* gamma = (const float*)d_in[7];
  const float* beta  = (const float*)d_in[8];
  const float* mean  = (const float*)d_in[9];
  const float* var   = (const float*)d_in[10];
  float* out = (float*)d_out;

  char* ws = (char*)d_ws;
  unsigned short* xt    = (unsigned short*)(ws);                       //  9,437,184 B
  unsigned short* wfrag = (unsigned short*)(ws + 9437184);             //  1,179,648 B
  unsigned short* w6p   = (unsigned short*)(ws + 9437184 + 1179648);   //     73,728 B

  k_pre<<<1008, 256, 0, stream>>>(x, w_df, w_tm, w_tr, xt, wfrag, w6p);
  k_fused<<<576, 512, 0, stream>>>(xt, wfrag, w6p, b_tm, b_tr, x,
                                   gamma, beta, mean, var, out);
}